// Round 1
// baseline (160.330 us; speedup 1.0000x reference)
//
#include <hip/hip_runtime.h>

#define B_IMG 32
#define N_A   200000
#define N_C   10000

// focal element, exactly mirroring reference fp32 math:
// c = sigmoid(x); t=1: 0.25*(1-c)^2*(-log c); t=0: 0.75*c^2*(-log(1-c))
__device__ __forceinline__ float focal_elem(float x, bool t) {
    float c = 1.0f / (1.0f + expf(-x));
    if (t) {
        float om = 1.0f - c;
        return 0.25f * om * om * (-logf(c));
    } else {
        return 0.75f * c * c * (-logf(1.0f - c));
    }
}

__device__ __forceinline__ double wave_red(double v) {
#pragma unroll
    for (int o = 32; o; o >>= 1) v += __shfl_down(v, o, 64);
    return v;
}

__global__ void init_ws(double* ws) {
    int i = threadIdx.x;
    if (i < 3 * B_IMG) ws[i] = 0.0;
}

// ws layout (doubles): [0,B): bbox focal sum | [B,2B): n_pos | [2B,3B): cls focal sum
__global__ __launch_bounds__(256) void bbox_kernel(
    const float* __restrict__ bd, const float* __restrict__ anc,
    const float* __restrict__ ann, double* __restrict__ ws)
{
    __shared__ float bsh[B_IMG * 4];
    __shared__ double sred[2][4];
    const int tid = threadIdx.x;
    if (tid < B_IMG * 4) {
        int j = tid >> 2, k = tid & 3;
        bsh[tid] = ann[j * 7 + k];
    }
    __syncthreads();

    const int nch = gridDim.x;
    const int chunk = (N_A + nch - 1) / nch;
    const int a0 = blockIdx.x * chunk;
    const int a1 = min(a0 + chunk, N_A);
    const int lane = tid & 63, wv = tid >> 6;

    for (int j = 0; j < B_IMG; ++j) {
        const float b0 = bsh[j*4+0], b1 = bsh[j*4+1], b2 = bsh[j*4+2], b3 = bsh[j*4+3];
        const float barea = (b2 - b0) * (b3 - b1);
        const float* bdr = bd + (size_t)j * N_A;
        float fsum = 0.0f;
        float cnt  = 0.0f;
        for (int i = a0 + tid; i < a1; i += 256) {
            const float4 av = ((const float4*)anc)[i];   // x0,y0,x1,y1
            float iw = fmaxf(fminf(av.z, b2) - fmaxf(av.x, b0), 0.0f);
            float ih = fmaxf(fminf(av.w, b3) - fmaxf(av.y, b1), 0.0f);
            float inter = iw * ih;
            float ua = fmaxf((av.z - av.x) * (av.w - av.y) + barea - inter, 1e-8f);
            bool pos = (inter / ua) >= 0.5f;
            float x = bdr[i];
            fsum += focal_elem(x, pos);
            cnt  += pos ? 1.0f : 0.0f;
        }
        double fv = wave_red((double)fsum);
        double cv = wave_red((double)cnt);
        if (lane == 0) { sred[0][wv] = fv; sred[1][wv] = cv; }
        __syncthreads();
        if (tid == 0) {
            double ft = sred[0][0] + sred[0][1] + sred[0][2] + sred[0][3];
            double ct = sred[1][0] + sred[1][1] + sred[1][2] + sred[1][3];
            atomicAdd(&ws[j], ft);
            atomicAdd(&ws[B_IMG + j], ct);
        }
        __syncthreads();
    }
}

__global__ __launch_bounds__(256) void cls_kernel(
    const float* __restrict__ cls, const float* __restrict__ ann,
    double* __restrict__ ws)
{
    const int j = blockIdx.x;
    const int n0 = (int)ann[j*7+4], n1 = (int)ann[j*7+5], n2 = (int)ann[j*7+6];
    const int tid = threadIdx.x;
    const float* cj = cls + (size_t)j * N_C;
    float fsum = 0.0f;
    for (int i = tid; i < N_C; i += 256) {
        bool t = (i == n0) || (i == n1) || (i == n2);
        fsum += focal_elem(cj[i], t);
    }
    __shared__ double sred[4];
    double v = wave_red((double)fsum);
    int lane = tid & 63, wv = tid >> 6;
    if (lane == 0) sred[wv] = v;
    __syncthreads();
    if (tid == 0) ws[2 * B_IMG + j] = sred[0] + sred[1] + sred[2] + sred[3];
}

__global__ void final_kernel(
    const float* __restrict__ anc, const float* __restrict__ ann,
    const float* __restrict__ reg, const double* __restrict__ ws,
    float* __restrict__ out)
{
    int t = threadIdx.x;
    double cl = 0.0, bl = 0.0, rl = 0.0;
    if (t < B_IMG) {
        int j = t;
        double npos = ws[B_IMG + j];
        cl = ws[2 * B_IMG + j] / (double)N_C;
        bl = ws[j] / (double)N_A;
        float b0 = ann[j*7+0], b1 = ann[j*7+1], b2 = ann[j*7+2], b3 = ann[j*7+3];
        float gw_raw = b2 - b0, gh_raw = b3 - b1;
        float gx = b0 + 0.5f * gw_raw, gy = b1 + 0.5f * gh_raw;
        float gw = fmaxf(gw_raw, 1.0f), gh = fmaxf(gh_raw, 1.0f);
        double s[2];
#pragma unroll
        for (int p = 0; p < 2; ++p) {
            float x0 = anc[p*4+0], y0 = anc[p*4+1], x1 = anc[p*4+2], y1 = anc[p*4+3];
            float aw = x1 - x0, ah = y1 - y0;
            float ax = x0 + 0.5f * aw, ay = y0 + 0.5f * ah;
            float tg[4];
            tg[0] = ((gx - ax) / aw) / 0.1f;
            tg[1] = ((gy - ay) / ah) / 0.1f;
            tg[2] = logf(gw / aw) / 0.2f;
            tg[3] = logf(gh / ah) / 0.2f;
            const float* rj = reg + (size_t)j * N_A * 4 + p * 4;
            double ssum = 0.0;
#pragma unroll
            for (int k = 0; k < 4; ++k) {
                float d = fabsf(tg[k] - rj[k]);
                float v = (d <= (1.0f / 9.0f)) ? (0.5f * 9.0f * d * d) : (d - 0.5f / 9.0f);
                ssum += (double)v;
            }
            s[p] = ssum;
        }
        double rlv = (((double)N_A - npos) * s[0] + npos * s[1]) / (4.0 * (double)N_A);
        rl = (npos > 0.0) ? rlv : 0.0;
    }
    cl = wave_red(cl);
    bl = wave_red(bl);
    rl = wave_red(rl);
    if (t == 0) {
        out[0] = (float)(cl / B_IMG);
        out[1] = (float)(bl / B_IMG);
        out[2] = (float)(rl / B_IMG);
    }
}

extern "C" void kernel_launch(void* const* d_in, const int* in_sizes, int n_in,
                              void* d_out, int out_size, void* d_ws, size_t ws_size,
                              hipStream_t stream) {
    const float* cls = (const float*)d_in[0];   // (32, 10000)
    const float* reg = (const float*)d_in[1];   // (32, 200000, 4)
    const float* bd  = (const float*)d_in[2];   // (32, 200000)
    const float* anc = (const float*)d_in[3];   // (1, 200000, 4)
    const float* ann = (const float*)d_in[4];   // (32, 1, 7)
    float* out = (float*)d_out;                 // 3 floats
    double* ws = (double*)d_ws;

    hipLaunchKernelGGL(init_ws, dim3(1), dim3(128), 0, stream, ws);
    hipLaunchKernelGGL(bbox_kernel, dim3(512), dim3(256), 0, stream, bd, anc, ann, ws);
    hipLaunchKernelGGL(cls_kernel, dim3(B_IMG), dim3(256), 0, stream, cls, ann, ws);
    hipLaunchKernelGGL(final_kernel, dim3(1), dim3(64), 0, stream, anc, ann, reg, ws, out);
}

// Round 2
// 21.553 us; speedup vs baseline: 7.4388x; 7.4388x over previous
//
#include <hip/hip_runtime.h>

#define B_IMG 32
#define N_A   200000
#define N_C   10000

#define NCH   32            // anchor chunks per image
#define CHUNK (N_A / NCH)   // 6250
#define NCC   4             // cls chunks per image
#define CCHUNK (N_C / NCC)  // 2500

// ws layout (doubles):
// [0, 1024)        bbox focal partial  [j*NCH + ch]
// [1024, 2048)     pos-count partial   [j*NCH + ch]
// [2048, 2176)     cls focal partial   [j*NCC + cc]
#define WS_FOCAL 0
#define WS_CNT   (B_IMG * NCH)
#define WS_CLS   (2 * B_IMG * NCH)

// c = sigmoid(x); t=1: 0.25*(1-c)^2*(-log c); t=0: 0.75*c^2*(-log(1-c))
// -log(c) = log(1+e) with e = exp(-x);  -log(1-c) = x + log(1+e);  1-c = e*c
__device__ __forceinline__ float focal_elem(float x, bool t) {
    float e = __expf(-x);
    float r = __builtin_amdgcn_rcpf(1.0f + e);   // c
    float L = __logf(1.0f + e);                  // softplus(-x)
    if (t) { float om = e * r; return 0.25f * om * om * L; }
    else   { return 0.75f * r * r * (x + L); }
}

__device__ __forceinline__ double wave_red(double v) {
#pragma unroll
    for (int o = 32; o; o >>= 1) v += __shfl_down(v, o, 64);
    return v;
}

// blocks [0,1024): bbox focal, block = (j, anchor chunk)
// blocks [1024,1152): cls focal, block = (j, cls chunk)
__global__ __launch_bounds__(256) void main_kernel(
    const float* __restrict__ cls, const float* __restrict__ bd,
    const float* __restrict__ anc, const float* __restrict__ ann,
    double* __restrict__ ws)
{
    const int tid = threadIdx.x;
    const int lane = tid & 63, wv = tid >> 6;
    __shared__ double sred[2][4];

    if (blockIdx.x < B_IMG * NCH) {
        const int j  = blockIdx.x >> 5;     // image
        const int ch = blockIdx.x & 31;     // anchor chunk
        const int a0 = ch * CHUNK;

        const float b0 = ann[j*7+0], b1 = ann[j*7+1], b2 = ann[j*7+2], b3 = ann[j*7+3];
        const float barea = (b2 - b0) * (b3 - b1);
        const float* __restrict__ bdr = bd + (size_t)j * N_A;

        float fsum = 0.0f, cnt = 0.0f;
        for (int i = a0 + tid; i < a0 + CHUNK; i += 256) {
            const float4 av = ((const float4*)anc)[i];   // x0,y0,x1,y1
            float iw = fmaxf(fminf(av.z, b2) - fmaxf(av.x, b0), 0.0f);
            float ih = fmaxf(fminf(av.w, b3) - fmaxf(av.y, b1), 0.0f);
            float inter = iw * ih;
            float ua = fmaxf((av.z - av.x) * (av.w - av.y) + barea - inter, 1e-8f);
            bool pos = (2.0f * inter >= ua);             // inter/ua >= 0.5
            fsum += focal_elem(bdr[i], pos);
            cnt  += pos ? 1.0f : 0.0f;
        }
        double fv = wave_red((double)fsum);
        double cv = wave_red((double)cnt);
        if (lane == 0) { sred[0][wv] = fv; sred[1][wv] = cv; }
        __syncthreads();
        if (tid == 0) {
            ws[WS_FOCAL + j * NCH + ch] = sred[0][0] + sred[0][1] + sred[0][2] + sred[0][3];
            ws[WS_CNT   + j * NCH + ch] = sred[1][0] + sred[1][1] + sred[1][2] + sred[1][3];
        }
    } else {
        const int bb = blockIdx.x - B_IMG * NCH;
        const int j  = bb >> 2;             // image
        const int cc = bb & 3;              // cls chunk
        const int c0 = cc * CCHUNK;
        const int n0 = (int)ann[j*7+4], n1 = (int)ann[j*7+5], n2 = (int)ann[j*7+6];
        const float* __restrict__ cj = cls + (size_t)j * N_C;
        float fsum = 0.0f;
        for (int i = c0 + tid; i < c0 + CCHUNK; i += 256) {
            bool t = (i == n0) || (i == n1) || (i == n2);
            fsum += focal_elem(cj[i], t);
        }
        double v = wave_red((double)fsum);
        if (lane == 0) sred[0][wv] = v;
        __syncthreads();
        if (tid == 0)
            ws[WS_CLS + j * NCC + cc] = sred[0][0] + sred[0][1] + sred[0][2] + sred[0][3];
    }
}

__global__ void final_kernel(
    const float* __restrict__ anc, const float* __restrict__ ann,
    const float* __restrict__ reg, const double* __restrict__ ws,
    float* __restrict__ out)
{
    int t = threadIdx.x;
    double cl = 0.0, bl = 0.0, rl = 0.0;
    if (t < B_IMG) {
        int j = t;
        double fsum = 0.0, npos = 0.0, csum = 0.0;
        for (int ch = 0; ch < NCH; ++ch) {
            fsum += ws[WS_FOCAL + j * NCH + ch];
            npos += ws[WS_CNT   + j * NCH + ch];
        }
        for (int cc = 0; cc < NCC; ++cc) csum += ws[WS_CLS + j * NCC + cc];
        cl = csum / (double)N_C;
        bl = fsum / (double)N_A;

        float b0 = ann[j*7+0], b1 = ann[j*7+1], b2 = ann[j*7+2], b3 = ann[j*7+3];
        float gw_raw = b2 - b0, gh_raw = b3 - b1;
        float gx = b0 + 0.5f * gw_raw, gy = b1 + 0.5f * gh_raw;
        float gw = fmaxf(gw_raw, 1.0f), gh = fmaxf(gh_raw, 1.0f);
        double s[2];
#pragma unroll
        for (int p = 0; p < 2; ++p) {
            float x0 = anc[p*4+0], y0 = anc[p*4+1], x1 = anc[p*4+2], y1 = anc[p*4+3];
            float aw = x1 - x0, ah = y1 - y0;
            float ax = x0 + 0.5f * aw, ay = y0 + 0.5f * ah;
            float tg[4];
            tg[0] = ((gx - ax) / aw) / 0.1f;
            tg[1] = ((gy - ay) / ah) / 0.1f;
            tg[2] = logf(gw / aw) / 0.2f;
            tg[3] = logf(gh / ah) / 0.2f;
            const float* rj = reg + (size_t)j * N_A * 4 + p * 4;
            double ssum = 0.0;
#pragma unroll
            for (int k = 0; k < 4; ++k) {
                float d = fabsf(tg[k] - rj[k]);
                float v = (d <= (1.0f / 9.0f)) ? (0.5f * 9.0f * d * d) : (d - 0.5f / 9.0f);
                ssum += (double)v;
            }
            s[p] = ssum;
        }
        double rlv = (((double)N_A - npos) * s[0] + npos * s[1]) / (4.0 * (double)N_A);
        rl = (npos > 0.0) ? rlv : 0.0;
    }
    cl = wave_red(cl);
    bl = wave_red(bl);
    rl = wave_red(rl);
    if (t == 0) {
        out[0] = (float)(cl / B_IMG);
        out[1] = (float)(bl / B_IMG);
        out[2] = (float)(rl / B_IMG);
    }
}

extern "C" void kernel_launch(void* const* d_in, const int* in_sizes, int n_in,
                              void* d_out, int out_size, void* d_ws, size_t ws_size,
                              hipStream_t stream) {
    const float* cls = (const float*)d_in[0];   // (32, 10000)
    const float* reg = (const float*)d_in[1];   // (32, 200000, 4)
    const float* bd  = (const float*)d_in[2];   // (32, 200000)
    const float* anc = (const float*)d_in[3];   // (1, 200000, 4)
    const float* ann = (const float*)d_in[4];   // (32, 1, 7)
    float* out = (float*)d_out;                 // 3 floats
    double* ws = (double*)d_ws;

    hipLaunchKernelGGL(main_kernel, dim3(B_IMG * NCH + B_IMG * NCC), dim3(256), 0, stream,
                       cls, bd, anc, ann, ws);
    hipLaunchKernelGGL(final_kernel, dim3(1), dim3(64), 0, stream, anc, ann, reg, ws, out);
}